// Round 4
// baseline (1406.883 us; speedup 1.0000x reference)
//
#include <hip/hip_runtime.h>
#include <hip/hip_cooperative_groups.h>

namespace cg = cooperative_groups;

// GCN block: delta = segment_sum( (x @ W^T)[source] * ew, target )
//          = segment_sum( x[source] * ew, target ) @ W^T   (linearity)
//
// R4: ONE cooperative kernel, phases separated by grid.sync():
//   P0 zero hist (+stage W->LDS)   P1 hist atomics      P2 chunk sums
//   P3 scan chunk sums (block 0)   P4 apply -> starts/cursor
//   P5 scatter (src,ew) pairs target-sorted
//   P6 segreduce (coalesced pair load + shfl bcast + 4-deep gathers)
//      + per-node 64x64 GEMM epilogue (W in LDS, float2, conflict-free)
// Removes 7 dispatch boundaries (~120us of fragmented preprocessing in R3).

#define D 64   // D_IN == D_OUT == 64

// ---------------- fallback: atomic edge scatter (R1) ----------------
__global__ __launch_bounds__(256) void gcn_scatter_kernel(
    const float* __restrict__ x, const float* __restrict__ ew,
    const int* __restrict__ src, const int* __restrict__ tgt,
    float* __restrict__ s, int n_edges)
{
    int lane = threadIdx.x & 63;
    int e = blockIdx.x * 4 + (threadIdx.x >> 6);
    if (e >= n_edges) return;
    int sn = src[e];
    int tn = tgt[e];
    float w = ew[e];
    float v = x[(size_t)sn * D + lane] * w;
    atomicAdd(&s[(size_t)tn * D + lane], v);
}

// ---------------- fallback: out = s @ W^T (R1) ----------------
__global__ __launch_bounds__(256) void gcn_gemm_kernel(
    const float* __restrict__ s, const float* __restrict__ W,
    float* __restrict__ out, int n_nodes)
{
    __shared__ float4 xs[64 * 17];
    const int tid  = threadIdx.x;
    const int lane = tid & 63;
    const int wid  = __builtin_amdgcn_readfirstlane(tid >> 6);
    const int row0 = blockIdx.x * 64;

    const float4* s4 = reinterpret_cast<const float4*>(s);
#pragma unroll
    for (int k = 0; k < 4; ++k) {
        int f  = tid + k * 256;
        int r  = f >> 4;
        int c4 = f & 15;
        float4 v = make_float4(0.f, 0.f, 0.f, 0.f);
        if (row0 + r < n_nodes)
            v = s4[(size_t)(row0 + r) * 16 + c4];
        xs[r * 17 + c4] = v;
    }
    __syncthreads();

    float acc[16];
#pragma unroll
    for (int j = 0; j < 16; ++j) acc[j] = 0.f;

    const int o0 = wid * 16;
    const float4* W4 = reinterpret_cast<const float4*>(W);
#pragma unroll
    for (int d4 = 0; d4 < 16; ++d4) {
        float4 xv = xs[lane * 17 + d4];
#pragma unroll
        for (int j = 0; j < 16; ++j) {
            float4 wv = W4[(size_t)(o0 + j) * 16 + d4];
            acc[j] += xv.x * wv.x + xv.y * wv.y + xv.z * wv.z + xv.w * wv.w;
        }
    }

    const int row = row0 + lane;
    if (row < n_nodes) {
        float4* out4 = reinterpret_cast<float4*>(out);
#pragma unroll
        for (int j4 = 0; j4 < 4; ++j4) {
            float4 v = make_float4(acc[j4 * 4 + 0], acc[j4 * 4 + 1],
                                   acc[j4 * 4 + 2], acc[j4 * 4 + 3]);
            out4[(size_t)row * 16 + wid * 4 + j4] = v;
        }
    }
}

// ---------------- R4: the cooperative mega-kernel ----------------
__global__ __launch_bounds__(256) void mega_kernel(
    const float* __restrict__ x, const float* __restrict__ W,
    const float* __restrict__ ew, const int* __restrict__ src,
    const int* __restrict__ tgt, int* __restrict__ hist,
    int* __restrict__ starts, int* __restrict__ cursor,
    int* __restrict__ blkSums, int2* __restrict__ pairs,
    float* __restrict__ out, int n_nodes, int n_edges)
{
    cg::grid_group gg = cg::this_grid();

    __shared__ float Wl[64 * 66];     // W[o][d] at Wl[o*66+d]; pad 66 -> float2 conflict-free
    __shared__ float accRow[4][64];
    __shared__ int   lds_i[256];

    const int tid  = threadIdx.x;
    const int gsz  = gridDim.x * 256;
    const int gtid = blockIdx.x * 256 + tid;

    // ---- P0: zero hist; stage W into LDS (persists all phases) ----
    for (int i = gtid; i < n_nodes; i += gsz) hist[i] = 0;
    for (int i = tid; i < 64 * 64; i += 256)
        Wl[(i >> 6) * 66 + (i & 63)] = W[i];
    __threadfence();
    gg.sync();

    // ---- P1: histogram of targets ----
    for (int i = gtid; i < n_edges; i += gsz) atomicAdd(&hist[tgt[i]], 1);
    gg.sync();

    // ---- P2: chunk sums (1024 nodes/chunk) ----
    const int nb = (n_nodes + 1023) >> 10;
    for (int c = blockIdx.x; c < nb; c += gridDim.x) {
        const int base = c * 1024 + tid * 4;
        int ssum = 0;
#pragma unroll
        for (int k = 0; k < 4; ++k)
            if (base + k < n_nodes) ssum += hist[base + k];
        lds_i[tid] = ssum;
        __syncthreads();
        for (int off = 128; off > 0; off >>= 1) {
            if (tid < off) lds_i[tid] += lds_i[tid + off];
            __syncthreads();
        }
        if (tid == 0) blkSums[c] = lds_i[0];
        __syncthreads();
    }
    __threadfence();
    gg.sync();

    // ---- P3: exclusive scan of blkSums[0..nb), nb <= 256, block 0 only ----
    if (blockIdx.x == 0) {
        int v = (tid < nb) ? blkSums[tid] : 0;
        lds_i[tid] = v;
        __syncthreads();
        for (int off = 1; off < 256; off <<= 1) {
            int a = (tid >= off) ? lds_i[tid - off] : 0;
            __syncthreads();
            lds_i[tid] += a;
            __syncthreads();
        }
        if (tid < nb) blkSums[tid] = lds_i[tid] - v;   // exclusive
        __threadfence();
    }
    gg.sync();

    // ---- P4: per-chunk exclusive scan + write starts/cursor ----
    for (int c = blockIdx.x; c < nb; c += gridDim.x) {
        const int base = c * 1024 + tid * 4;
        int v0 = 0, v1 = 0, v2 = 0, v3 = 0;
        if (base + 0 < n_nodes) v0 = hist[base + 0];
        if (base + 1 < n_nodes) v1 = hist[base + 1];
        if (base + 2 < n_nodes) v2 = hist[base + 2];
        if (base + 3 < n_nodes) v3 = hist[base + 3];
        const int tsum = v0 + v1 + v2 + v3;
        lds_i[tid] = tsum;
        __syncthreads();
        for (int off = 1; off < 256; off <<= 1) {
            int a = (tid >= off) ? lds_i[tid - off] : 0;
            __syncthreads();
            lds_i[tid] += a;
            __syncthreads();
        }
        int pre = blkSums[c] + lds_i[tid] - tsum;
        if (base + 0 < n_nodes) { starts[base + 0] = pre; cursor[base + 0] = pre; pre += v0; }
        if (base + 1 < n_nodes) { starts[base + 1] = pre; cursor[base + 1] = pre; pre += v1; }
        if (base + 2 < n_nodes) { starts[base + 2] = pre; cursor[base + 2] = pre; pre += v2; }
        if (base + 3 < n_nodes) { starts[base + 3] = pre; cursor[base + 3] = pre; }
        __syncthreads();
    }
    __threadfence();
    gg.sync();

    // ---- P5: scatter packed (src, ew) into target-sorted order ----
    for (int i = gtid; i < n_edges; i += gsz) {
        int t = tgt[i];
        int pos = atomicAdd(&cursor[t], 1);
        pairs[pos] = make_int2(src[i], __float_as_int(ew[i]));
    }
    __threadfence();
    gg.sync();

    // ---- P6: segreduce + GEMM epilogue, one wave per node, grid-stride ----
    const int lane = tid & 63;
    const int wv   = tid >> 6;
    const int total_waves = gridDim.x * 4;

    for (int t = blockIdx.x * 4 + wv; t < n_nodes; t += total_waves) {
        const int beg = starts[t];
        const int end = (t + 1 < n_nodes) ? starts[t + 1] : n_edges;
        float acc = 0.f;

        for (int base = beg; base < end; base += 64) {
            const int rem = end - base;
            const int cnt = rem < 64 ? rem : 64;
            int2 pr = make_int2(0, 0);
            if (lane < cnt) pr = pairs[base + lane];   // coalesced 512B

            int j = 0;
            for (; j + 4 <= cnt; j += 4) {
                int   s0 = __shfl(pr.x, j + 0); float w0 = __int_as_float(__shfl(pr.y, j + 0));
                int   s1 = __shfl(pr.x, j + 1); float w1 = __int_as_float(__shfl(pr.y, j + 1));
                int   s2 = __shfl(pr.x, j + 2); float w2 = __int_as_float(__shfl(pr.y, j + 2));
                int   s3 = __shfl(pr.x, j + 3); float w3 = __int_as_float(__shfl(pr.y, j + 3));
                float x0 = x[(size_t)s0 * D + lane];   // 4 independent gathers in flight
                float x1 = x[(size_t)s1 * D + lane];
                float x2 = x[(size_t)s2 * D + lane];
                float x3 = x[(size_t)s3 * D + lane];
                acc += w0 * x0; acc += w1 * x1; acc += w2 * x2; acc += w3 * x3;
            }
            for (; j < cnt; ++j) {
                int   sj = __shfl(pr.x, j);
                float wj = __int_as_float(__shfl(pr.y, j));
                acc += wj * x[(size_t)sj * D + lane];
            }
        }

        // epilogue: out[t][o] = sum_d acc[d] * W[o][d], o = lane
        accRow[wv][lane] = acc;
        asm volatile("s_waitcnt lgkmcnt(0)" ::: "memory");   // wave-internal LDS fence

        float o_acc = 0.f;
        const float2* w2 = reinterpret_cast<const float2*>(&Wl[lane * 66]); // 264B stride, 8B-aligned
        const float2* a2 = reinterpret_cast<const float2*>(&accRow[wv][0]);
#pragma unroll
        for (int d2 = 0; d2 < 32; ++d2) {
            float2 wq = w2[d2];        // bank (lane+d2)%32 over a pair -> 2-way, free
            float2 aq = a2[d2];        // broadcast
            o_acc += aq.x * wq.x + aq.y * wq.y;
        }
        out[(size_t)t * D + lane] = o_acc;
        asm volatile("s_waitcnt lgkmcnt(0)" ::: "memory");   // reads done before next overwrite
    }
}

extern "C" void kernel_launch(void* const* d_in, const int* in_sizes, int n_in,
                              void* d_out, int out_size, void* d_ws, size_t ws_size,
                              hipStream_t stream)
{
    const float* x   = (const float*)d_in[0];
    const float* W   = (const float*)d_in[1];
    const float* ew  = (const float*)d_in[2];
    const int*   src = (const int*)d_in[3];
    const int*   tgt = (const int*)d_in[4];

    const int n_nodes = in_sizes[0] / D;
    const int n_edges = in_sizes[2];

    // ---- workspace layout ----
    int* hist    = (int*)d_ws;                    // n_nodes
    int* starts  = hist + n_nodes;                // n_nodes
    int* cursor  = starts + n_nodes;              // n_nodes
    int* blkSums = cursor + n_nodes;              // 1024
    size_t off_i = ((size_t)3 * n_nodes + 1024 + 1) & ~(size_t)1;  // 8B-align
    int2* pairs  = (int2*)((int*)d_ws + off_i);   // n_edges int2

    const size_t need = (off_i + 2 * (size_t)n_edges) * sizeof(int);
    const int nb = (n_nodes + 1023) >> 10;

    bool coop_ok = (ws_size >= need) && (nb <= 256);
    int dev = 0;
    (void)hipGetDevice(&dev);
    int coop_attr = 0;
    if (coop_ok && hipDeviceGetAttribute(&coop_attr, hipDeviceAttributeCooperativeLaunch, dev) == hipSuccess)
        coop_ok = (coop_attr != 0);
    else if (coop_ok && coop_attr == 0)
        coop_ok = false;

    int grid = 0;
    if (coop_ok) {
        int max_blk_per_cu = 0;
        if (hipOccupancyMaxActiveBlocksPerMultiprocessor(
                &max_blk_per_cu, (const void*)mega_kernel, 256, 0) != hipSuccess ||
            max_blk_per_cu <= 0)
            coop_ok = false;
        else {
            int num_cu = 0;
            if (hipDeviceGetAttribute(&num_cu, hipDeviceAttributeMultiprocessorCount, dev) != hipSuccess ||
                num_cu <= 0)
                num_cu = 256;   // MI355X
            long cap = (long)max_blk_per_cu * num_cu;
            grid = (int)(cap < 2048 ? cap : 2048);
            if (grid < 1) coop_ok = false;
        }
    }

    if (coop_ok) {
        float* outp = (float*)d_out;
        int nn = n_nodes, ne = n_edges;
        void* args[] = { (void*)&x, (void*)&W, (void*)&ew, (void*)&src, (void*)&tgt,
                         (void*)&hist, (void*)&starts, (void*)&cursor, (void*)&blkSums,
                         (void*)&pairs, (void*)&outp, (void*)&nn, (void*)&ne };
        hipError_t err = hipLaunchCooperativeKernel((const void*)mega_kernel,
                                                    dim3(grid), dim3(256),
                                                    args, 0, stream);
        if (err == hipSuccess) return;
        // fall through to atomic fallback on launch failure
    }

    // ---- fallback: R1 atomic path (needs n_nodes*D floats of ws) ----
    float* s = (float*)d_ws;
    hipMemsetAsync(s, 0, (size_t)n_nodes * D * sizeof(float), stream);
    gcn_scatter_kernel<<<(n_edges + 3) / 4, 256, 0, stream>>>(x, ew, src, tgt, s, n_edges);
    gcn_gemm_kernel<<<(n_nodes + 63) / 64, 256, 0, stream>>>(s, W, (float*)d_out, n_nodes);
}

// Round 5
// 174.206 us; speedup vs baseline: 8.0760x; 8.0760x over previous
//
#include <hip/hip_runtime.h>

// GCN block: delta = segment_sum( (x @ W^T)[source] * ew, target )
//          = segment_sum( x[source] * ew, target ) @ W^T   (linearity)
//
// R5: R3 multi-kernel structure (cooperative R4 regressed 7x: grid.sync spin
// + cross-XCD fences dominated). Changes vs R3:
//  - fused segreduce: wave-uniform SCALAR pair loads (no ds_bpermute shuffles)
//    + 8-deep unrolled independent x-row gathers.
//  - hist reads tgt vectorized.

#define D 64   // D_IN == D_OUT == 64

// ---------------- fallback: atomic edge scatter (R1) ----------------
__global__ __launch_bounds__(256) void gcn_scatter_kernel(
    const float* __restrict__ x, const float* __restrict__ ew,
    const int* __restrict__ src, const int* __restrict__ tgt,
    float* __restrict__ s, int n_edges)
{
    int lane = threadIdx.x & 63;
    int e = blockIdx.x * 4 + (threadIdx.x >> 6);
    if (e >= n_edges) return;
    int sn = src[e];
    int tn = tgt[e];
    float w = ew[e];
    float v = x[(size_t)sn * D + lane] * w;
    atomicAdd(&s[(size_t)tn * D + lane], v);
}

// ---------------- fallback: out = s @ W^T (R1) ----------------
__global__ __launch_bounds__(256) void gcn_gemm_kernel(
    const float* __restrict__ s, const float* __restrict__ W,
    float* __restrict__ out, int n_nodes)
{
    __shared__ float4 xs[64 * 17];
    const int tid  = threadIdx.x;
    const int lane = tid & 63;
    const int wid  = __builtin_amdgcn_readfirstlane(tid >> 6);
    const int row0 = blockIdx.x * 64;

    const float4* s4 = reinterpret_cast<const float4*>(s);
#pragma unroll
    for (int k = 0; k < 4; ++k) {
        int f  = tid + k * 256;
        int r  = f >> 4;
        int c4 = f & 15;
        float4 v = make_float4(0.f, 0.f, 0.f, 0.f);
        if (row0 + r < n_nodes)
            v = s4[(size_t)(row0 + r) * 16 + c4];
        xs[r * 17 + c4] = v;
    }
    __syncthreads();

    float acc[16];
#pragma unroll
    for (int j = 0; j < 16; ++j) acc[j] = 0.f;

    const int o0 = wid * 16;
    const float4* W4 = reinterpret_cast<const float4*>(W);
#pragma unroll
    for (int d4 = 0; d4 < 16; ++d4) {
        float4 xv = xs[lane * 17 + d4];
#pragma unroll
        for (int j = 0; j < 16; ++j) {
            float4 wv = W4[(size_t)(o0 + j) * 16 + d4];
            acc[j] += xv.x * wv.x + xv.y * wv.y + xv.z * wv.z + xv.w * wv.w;
        }
    }

    const int row = row0 + lane;
    if (row < n_nodes) {
        float4* out4 = reinterpret_cast<float4*>(out);
#pragma unroll
        for (int j4 = 0; j4 < 4; ++j4) {
            float4 v = make_float4(acc[j4 * 4 + 0], acc[j4 * 4 + 1],
                                   acc[j4 * 4 + 2], acc[j4 * 4 + 3]);
            out4[(size_t)row * 16 + wid * 4 + j4] = v;
        }
    }
}

// ---------------- 1. histogram of targets ----------------
__global__ __launch_bounds__(256) void hist_kernel(
    const int* __restrict__ tgt, int* __restrict__ hist, int n_edges)
{
    int base = (blockIdx.x * 256 + threadIdx.x) * 4;
    if (base + 3 < n_edges) {
        int4 t4 = *reinterpret_cast<const int4*>(tgt + base);
        atomicAdd(&hist[t4.x], 1);
        atomicAdd(&hist[t4.y], 1);
        atomicAdd(&hist[t4.z], 1);
        atomicAdd(&hist[t4.w], 1);
    } else {
        for (int i = base; i < n_edges; ++i) atomicAdd(&hist[tgt[i]], 1);
    }
}

// ---------------- 2a. per-chunk sums (chunk = 1024) ----------------
__global__ __launch_bounds__(256) void chunk_sum_kernel(
    const int* __restrict__ hist, int* __restrict__ blkSums, int n)
{
    __shared__ int lds[256];
    const int tid = threadIdx.x;
    const int base = blockIdx.x * 1024 + tid * 4;
    int4 v = make_int4(0, 0, 0, 0);
    if (base + 3 < n) v = *reinterpret_cast<const int4*>(hist + base);
    else {
        if (base + 0 < n) v.x = hist[base + 0];
        if (base + 1 < n) v.y = hist[base + 1];
        if (base + 2 < n) v.z = hist[base + 2];
    }
    lds[tid] = v.x + v.y + v.z + v.w;
    __syncthreads();
    for (int off = 128; off > 0; off >>= 1) {
        if (tid < off) lds[tid] += lds[tid + off];
        __syncthreads();
    }
    if (tid == 0) blkSums[blockIdx.x] = lds[0];
}

// ---------------- 2b. exclusive scan of chunk sums (nb <= 1024) ------------
__global__ __launch_bounds__(1024) void scan_blk_kernel(
    int* __restrict__ blkSums, int nb)
{
    __shared__ int lds[1024];
    const int tid = threadIdx.x;
    int v = (tid < nb) ? blkSums[tid] : 0;
    lds[tid] = v;
    __syncthreads();
    for (int off = 1; off < 1024; off <<= 1) {
        int a = (tid >= off) ? lds[tid - off] : 0;
        __syncthreads();
        lds[tid] += a;
        __syncthreads();
    }
    if (tid < nb) blkSums[tid] = lds[tid] - v;   // exclusive
}

// ---------------- 2c. per-chunk exclusive scan + apply offsets -------------
__global__ __launch_bounds__(256) void scan_apply_kernel(
    const int* __restrict__ hist, const int* __restrict__ blkSums,
    int* __restrict__ starts, int* __restrict__ cursor, int n)
{
    __shared__ int lds[256];
    const int tid = threadIdx.x;
    const int base = blockIdx.x * 1024 + tid * 4;
    int4 v = make_int4(0, 0, 0, 0);
    if (base + 3 < n) v = *reinterpret_cast<const int4*>(hist + base);
    else {
        if (base + 0 < n) v.x = hist[base + 0];
        if (base + 1 < n) v.y = hist[base + 1];
        if (base + 2 < n) v.z = hist[base + 2];
    }
    const int tsum = v.x + v.y + v.z + v.w;
    lds[tid] = tsum;
    __syncthreads();
    for (int off = 1; off < 256; off <<= 1) {
        int a = (tid >= off) ? lds[tid - off] : 0;
        __syncthreads();
        lds[tid] += a;
        __syncthreads();
    }
    int pre = blkSums[blockIdx.x] + lds[tid] - tsum;
    if (base + 0 < n) { starts[base + 0] = pre; cursor[base + 0] = pre; pre += v.x; }
    if (base + 1 < n) { starts[base + 1] = pre; cursor[base + 1] = pre; pre += v.y; }
    if (base + 2 < n) { starts[base + 2] = pre; cursor[base + 2] = pre; pre += v.z; }
    if (base + 3 < n) { starts[base + 3] = pre; cursor[base + 3] = pre; }
}

// ---------------- 3. scatter packed (src, ew) into target-sorted order -----
__global__ __launch_bounds__(256) void scatter_ids_kernel(
    const int* __restrict__ src, const int* __restrict__ tgt,
    const float* __restrict__ ew, int* __restrict__ cursor,
    int2* __restrict__ pairs, int n_edges)
{
    int i = blockIdx.x * 256 + threadIdx.x;
    if (i >= n_edges) return;
    int t = tgt[i];
    int pos = atomicAdd(&cursor[t], 1);
    pairs[pos] = make_int2(src[i], __float_as_int(ew[i]));   // one 8B write
}

// ---------------- 4. fused segreduce + 64x64 GEMM epilogue ----------------
// Grid-stride, one wave per node. Pair loads are wave-uniform -> scalar
// (s_load via sL1, sequential stream). 8 independent x-row gathers in flight.
__global__ __launch_bounds__(256) void fused_segreduce_gemm_kernel(
    const float* __restrict__ x, const int* __restrict__ starts,
    const int2* __restrict__ pairs, const float* __restrict__ W,
    float* __restrict__ out, int n_nodes, int n_edges, int total_waves)
{
    __shared__ float Wl[64 * 66];     // W[o][d] at Wl[o*66+d]; float2 conflict-free
    __shared__ float accRow[4][64];

    const int tid = threadIdx.x;
    for (int i = tid; i < 64 * 64; i += 256)
        Wl[(i >> 6) * 66 + (i & 63)] = W[i];
    __syncthreads();                  // only barrier; waves diverge after this

    const int lane = tid & 63;
    const int wv   = tid >> 6;

    for (int t0 = blockIdx.x * 4 + wv; t0 < n_nodes; t0 += total_waves) {
        const int t   = __builtin_amdgcn_readfirstlane(t0);
        const int beg = __builtin_amdgcn_readfirstlane(starts[t]);
        const int end = __builtin_amdgcn_readfirstlane(
                            (t + 1 < n_nodes) ? starts[t + 1] : n_edges);
        float acc = 0.f;

        int e = beg;
        for (; e + 8 <= end; e += 8) {
            // 8 wave-uniform pair loads (scalar) -> 8 independent gathers
            int2 p0 = pairs[e + 0]; int2 p1 = pairs[e + 1];
            int2 p2 = pairs[e + 2]; int2 p3 = pairs[e + 3];
            int2 p4 = pairs[e + 4]; int2 p5 = pairs[e + 5];
            int2 p6 = pairs[e + 6]; int2 p7 = pairs[e + 7];
            float x0 = x[(size_t)p0.x * D + lane];
            float x1 = x[(size_t)p1.x * D + lane];
            float x2 = x[(size_t)p2.x * D + lane];
            float x3 = x[(size_t)p3.x * D + lane];
            float x4 = x[(size_t)p4.x * D + lane];
            float x5 = x[(size_t)p5.x * D + lane];
            float x6 = x[(size_t)p6.x * D + lane];
            float x7 = x[(size_t)p7.x * D + lane];
            acc += __int_as_float(p0.y) * x0;
            acc += __int_as_float(p1.y) * x1;
            acc += __int_as_float(p2.y) * x2;
            acc += __int_as_float(p3.y) * x3;
            acc += __int_as_float(p4.y) * x4;
            acc += __int_as_float(p5.y) * x5;
            acc += __int_as_float(p6.y) * x6;
            acc += __int_as_float(p7.y) * x7;
        }
        for (; e < end; ++e) {
            int2 p = pairs[e];
            acc += __int_as_float(p.y) * x[(size_t)p.x * D + lane];
        }

        // ---- epilogue: out[t][o] = sum_d acc[d] * W[o][d], o = lane ----
        accRow[wv][lane] = acc;
        asm volatile("s_waitcnt lgkmcnt(0)" ::: "memory");   // wave-internal LDS fence

        float o_acc = 0.f;
        const float2* w2 = reinterpret_cast<const float2*>(&Wl[lane * 66]);
        const float2* a2 = reinterpret_cast<const float2*>(&accRow[wv][0]);
#pragma unroll
        for (int d2 = 0; d2 < 32; ++d2) {
            float2 wq = w2[d2];        // 2-way bank alias max -> free
            float2 aq = a2[d2];        // broadcast
            o_acc += aq.x * wq.x + aq.y * wq.y;
        }
        out[(size_t)t * D + lane] = o_acc;
        asm volatile("s_waitcnt lgkmcnt(0)" ::: "memory");   // drain reads before overwrite
    }
}

extern "C" void kernel_launch(void* const* d_in, const int* in_sizes, int n_in,
                              void* d_out, int out_size, void* d_ws, size_t ws_size,
                              hipStream_t stream)
{
    const float* x   = (const float*)d_in[0];
    const float* W   = (const float*)d_in[1];
    const float* ew  = (const float*)d_in[2];
    const int*   src = (const int*)d_in[3];
    const int*   tgt = (const int*)d_in[4];

    const int n_nodes = in_sizes[0] / D;
    const int n_edges = in_sizes[2];

    // ---- workspace layout ----
    int* hist    = (int*)d_ws;                    // n_nodes
    int* starts  = hist + n_nodes;                // n_nodes
    int* cursor  = starts + n_nodes;              // n_nodes
    int* blkSums = cursor + n_nodes;              // up to 1024
    size_t off_i = ((size_t)3 * n_nodes + 1024 + 1) & ~(size_t)1;  // 8B-align
    int2* pairs  = (int2*)((int*)d_ws + off_i);   // n_edges int2

    const size_t need = (off_i + 2 * (size_t)n_edges) * sizeof(int);

    const int eblocks = (n_edges + 255) / 256;

    if (ws_size < need) {
        // fallback: R1 atomic path (needs n_nodes*D floats)
        float* s = (float*)d_ws;
        hipMemsetAsync(s, 0, (size_t)n_nodes * D * sizeof(float), stream);
        gcn_scatter_kernel<<<(n_edges + 3) / 4, 256, 0, stream>>>(x, ew, src, tgt, s, n_edges);
        gcn_gemm_kernel<<<(n_nodes + 63) / 64, 256, 0, stream>>>(s, W, (float*)d_out, n_nodes);
        return;
    }

    const int nb = (n_nodes + 1023) / 1024;

    hipMemsetAsync(hist, 0, (size_t)n_nodes * sizeof(int), stream);
    hist_kernel<<<(n_edges + 1023) / 1024, 256, 0, stream>>>(tgt, hist, n_edges);
    chunk_sum_kernel<<<nb, 256, 0, stream>>>(hist, blkSums, n_nodes);
    scan_blk_kernel<<<1, 1024, 0, stream>>>(blkSums, nb);
    scan_apply_kernel<<<nb, 256, 0, stream>>>(hist, blkSums, starts, cursor, n_nodes);
    scatter_ids_kernel<<<eblocks, 256, 0, stream>>>(src, tgt, ew, cursor, pairs, n_edges);

    const int fblocks = 2048;                      // 8192 persistent waves
    fused_segreduce_gemm_kernel<<<fblocks, 256, 0, stream>>>(
        x, starts, pairs, W, (float*)d_out, n_nodes, n_edges, fblocks * 4);
}